// Round 6
// baseline (6742.999 us; speedup 1.0000x reference)
//
#include <hip/hip_runtime.h>
#include <hip/hip_bf16.h>

typedef unsigned short u16;
typedef unsigned int u32;
typedef unsigned long long u64;
typedef __attribute__((ext_vector_type(8))) short bf16x8;   // 8 bf16 (4 VGPRs)
typedef __attribute__((ext_vector_type(4))) float f32x4;

#define MFMA(a,b,c) __builtin_amdgcn_mfma_f32_16x16x32_bf16((a),(b),(c),0,0,0)
#define AGENT __HIP_MEMORY_SCOPE_AGENT

// ALL inputs and the output are FP32 (R5 diagnosis: no bf16 floor in harness
// threshold => _any_bf16 false; NaN from fp32-as-bf16 misreads). Weights are
// converted to bf16 fragments once at kernel start; h-state master is fp32 in
// registers; ws h-buffers are bf16 (MFMA input precision anyway).
//
// B=128, T=512, LAT=256, F2=64, H=512, DIN=320, 3H=1536
// 256 wgs: wg<128 -> GRU5 (rowgroup=wg>>4 of 8, slice=wg&15 of 16, 32 h-cols)
//          wg>=128 -> GRU6 (same split)
// iter t (514 total): GRU5 computes h5[t] (t<=511); GRU6 computes h6[t-1]
// (1<=t<=512); dec[t-2] emitted from staged h6[t-2] (t>=2).
// h5[s]/h6[s] live at ws parity s&1. Per-rowgroup monotonic barrier (32 wgs).

__device__ __forceinline__ u16 f2bf(float f) {
    u32 u = __float_as_uint(f);
    u32 r = (u + 0x7fffu + ((u >> 16) & 1u)) >> 16;
    return (u16)r;
}
__device__ __forceinline__ float bf2f(u16 v) { return __uint_as_float(((u32)v) << 16); }
__device__ __forceinline__ float sat01(float x) { return fminf(1.f, fmaxf(0.f, x)); }
__device__ __forceinline__ float ftanh(float x) {
    x = fminf(10.f, fmaxf(-10.f, x));
    float e = __expf(2.f * x);
    return (e - 1.f) / (e + 1.f);
}

// B-fragment from fp32 weights: lane holds B[k=k0+q8+j][n=colbase+l15], row stride 1536.
__device__ __forceinline__ bf16x8 loadB(const float* __restrict__ M, int k0, int colbase,
                                        int l15, int q8) {
    const float* p = M + (size_t)(k0 + q8) * 1536 + colbase + l15;
    bf16x8 r;
#pragma unroll
    for (int j = 0; j < 8; ++j) r[j] = (short)f2bf(p[(size_t)j * 1536]);
    return r;
}

// A-fragment from LDS: lane holds A[m=l15][k=colbase+q8+j]; 16B aligned -> ds_read_b128
__device__ __forceinline__ bf16x8 ldsA(const u16* s, int stride, int colbase, int l15, int q8) {
    return *(const bf16x8*)(s + l15 * stride + colbase + q8);
}

__global__ void zero_ws_kernel(u32* ws) {
    int i = blockIdx.x * 256 + threadIdx.x;
    if (i < 131328) ws[i] = 0u;  // h5bf[2][128][512] + h6bf[2][128][512] (u16) + barrier
}

__global__ void __launch_bounds__(256, 1)
gru_fused(const float* __restrict__ zin, const float* __restrict__ x2,
          const float* __restrict__ msk, const float* __restrict__ dmsk,
          const float* __restrict__ W5, const float* __restrict__ U5,
          const float* __restrict__ bi5, const float* __restrict__ br5,
          const float* __restrict__ W6, const float* __restrict__ U6,
          const float* __restrict__ bi6, const float* __restrict__ br6,
          const float* __restrict__ Wd, const float* __restrict__ bdp,
          float* __restrict__ out, u16* __restrict__ h5g,
          u16* __restrict__ h6g, u32* __restrict__ bar)
{
    const int wg = blockIdx.x;
    const bool is6 = wg >= 128;
    const int id = is6 ? wg - 128 : wg;
    const int slice = id & 15;          // 16 col-slices of 32 h-cols
    const int rgp = id >> 4;            // 8 rowgroups of 16 batch rows
    const int row0 = rgp << 4;
    const int sb = slice << 5;          // h-col base (0..480)
    const int tid = threadIdx.x;
    const int wv = tid >> 6, lane = tid & 63;
    const int l15 = lane & 15, q8 = (lane >> 4) << 3;

    __shared__ u16 stg[16 * 1032];
    __shared__ float exch[8 * 16 * 17];  // 8 C-tiles (z c0,z c1,r c0,r c1,xh c0,xh c1,ih c0,ih c1)

    const int ct = wv & 1;                // coltile within slice
    const int gMain = (wv < 2) ? 0 : 1;   // z for waves 0/1, r for waves 2/3
    const int colMain = gMain * 512 + sb + ct * 16;
    const int colH = 1024 + sb + ct * 16; // h-gate columns

    const float* bi = is6 ? bi6 : bi5;
    const float* br = is6 ? br6 : br5;
    const float biasM = bi[colMain + l15] + br[colMain + l15];      // z/r combined
    const float biasS = (wv < 2) ? bi[colH + l15] : br[colH + l15]; // xh / ih

    // ---- persistent register-resident B fragments (fp32 -> bf16 once) ----
    bf16x8 Bm[32], Bs[16];
    if (!is6) {
#pragma unroll
        for (int kt = 0; kt < 10; ++kt) Bm[kt] = loadB(W5, kt * 32, colMain, l15, q8);
#pragma unroll
        for (int kt = 0; kt < 16; ++kt) Bm[10 + kt] = loadB(U5, kt * 32, colMain, l15, q8);
        if (wv < 2) {
#pragma unroll
            for (int kt = 0; kt < 10; ++kt) Bs[kt] = loadB(W5, kt * 32, colH, l15, q8);
        } else {
#pragma unroll
            for (int kt = 0; kt < 16; ++kt) Bs[kt] = loadB(U5, kt * 32, colH, l15, q8);
        }
    } else {
#pragma unroll
        for (int kt = 0; kt < 16; ++kt) Bm[kt] = loadB(W6, kt * 32, colMain, l15, q8);
#pragma unroll
        for (int kt = 0; kt < 16; ++kt) Bm[16 + kt] = loadB(U6, kt * 32, colMain, l15, q8);
        if (wv < 2) {
#pragma unroll
            for (int kt = 0; kt < 16; ++kt) Bs[kt] = loadB(W6, kt * 32, colH, l15, q8);
        } else {
#pragma unroll
            for (int kt = 0; kt < 16; ++kt) Bs[kt] = loadB(U6, kt * 32, colH, l15, q8);
        }
    }

    // Dense head weights for GRU6 wave 0 (fp32)
    float wdv[8]; float bdv = 0.f;
    if (is6 && wv == 0) {
#pragma unroll
        for (int j = 0; j < 8; ++j) wdv[j] = Wd[lane * 8 + j];
        bdv = bdp[0];
    }

    // fp32 master h state (row=tid>>4, cols 2*(tid&15), 2*(tid&15)+1)
    float hold0 = 0.f, hold1 = 0.f;
    const int grow = tid >> 4, cp = tid & 15;
    const int c2p = cp >> 3, ccb = (cp & 7) * 2;

    const int r_ = tid >> 4, cth = tid & 15;  // staging coords: 16 threads per row
    const int b_ = row0 + r_;

    for (int t = 0; t < 514; ++t) {
        if (!is6) {
            if (t < 512) {
                // ---- stage masked x (fp32 inputs -> bf16, cols 0..319) ----
                float mk = msk[b_ * 512 + t];
                for (int c = cth; c < 320; c += 16) {
                    float v = (c < 256) ? zin[b_ * 256 + c]
                                        : x2[(b_ * 512 + t) * 64 + (c - 256)];
                    stg[r_ * 840 + c] = f2bf(v * mk);
                }
                // ---- stage h5[t-1] (bf16 in ws) via agent-scope atomic loads ----
                {
                    const u64* src = (const u64*)(h5g + ((t + 1) & 1) * 65536 +
                                                  (size_t)b_ * 512 + cth * 32);
                    u64* dst = (u64*)&stg[r_ * 840 + 320 + cth * 32];
#pragma unroll
                    for (int i = 0; i < 8; ++i)
                        dst[i] = __hip_atomic_load(&src[i], __ATOMIC_RELAXED, AGENT);
                }
                __syncthreads();
                // ---- MFMA: x-part K=320 (W5), h-part K=512 (U5) ----
                f32x4 a0 = {biasM, biasM, biasM, biasM};
                f32x4 a1 = {biasS, biasS, biasS, biasS};
                if (wv < 2) {  // z + xh
#pragma unroll
                    for (int kt = 0; kt < 10; ++kt) {
                        bf16x8 a = ldsA(stg, 840, kt * 32, l15, q8);
                        a0 = MFMA(a, Bm[kt], a0);
                        a1 = MFMA(a, Bs[kt], a1);
                    }
#pragma unroll
                    for (int kt = 0; kt < 16; ++kt) {
                        bf16x8 a = ldsA(stg, 840, 320 + kt * 32, l15, q8);
                        a0 = MFMA(a, Bm[10 + kt], a0);
                    }
                } else {       // r + ih
#pragma unroll
                    for (int kt = 0; kt < 10; ++kt) {
                        bf16x8 a = ldsA(stg, 840, kt * 32, l15, q8);
                        a0 = MFMA(a, Bm[kt], a0);
                    }
#pragma unroll
                    for (int kt = 0; kt < 16; ++kt) {
                        bf16x8 a = ldsA(stg, 840, 320 + kt * 32, l15, q8);
                        a0 = MFMA(a, Bm[10 + kt], a0);
                        a1 = MFMA(a, Bs[kt], a1);
                    }
                }
                {   // exchange C-tiles (C-layout: col=lane&15, row=(lane>>4)*4+reg)
                    int uM = gMain * 2 + ct, uS = (wv < 2 ? 4 + ct : 6 + ct);
#pragma unroll
                    for (int i = 0; i < 4; ++i) {
                        int rr = (lane >> 4) * 4 + i;
                        exch[uM * 272 + rr * 17 + l15] = a0[i];
                        exch[uS * 272 + rr * 17 + l15] = a1[i];
                    }
                }
                __syncthreads();
                // ---- gate math; fp32 state in regs, packed bf16 atomic store ----
                {
                    u32* hw32 = (u32*)(h5g + (t & 1) * 65536 + (size_t)row0 * 512);
                    int base0 = (0 + c2p) * 272 + grow * 17 + ccb;
                    int base1 = (2 + c2p) * 272 + grow * 17 + ccb;
                    int base2 = (4 + c2p) * 272 + grow * 17 + ccb;
                    int base3 = (6 + c2p) * 272 + grow * 17 + ccb;
                    float zv0 = exch[base0], zv1 = exch[base0 + 1];
                    float rv0 = exch[base1], rv1 = exch[base1 + 1];
                    float xh0 = exch[base2], xh1 = exch[base2 + 1];
                    float ih0 = exch[base3], ih1 = exch[base3 + 1];
                    float zg0 = sat01(0.2f * zv0 + 0.5f), zg1 = sat01(0.2f * zv1 + 0.5f);
                    float rt0 = sat01(0.2f * rv0 + 0.5f), rt1 = sat01(0.2f * rv1 + 0.5f);
                    float hh0 = ftanh(xh0 + rt0 * ih0), hh1 = ftanh(xh1 + rt1 * ih1);
                    float h0 = zg0 * hold0 + (1.f - zg0) * hh0;
                    float h1 = zg1 * hold1 + (1.f - zg1) * hh1;
                    hold0 = h0; hold1 = h1;
                    u32 pk = (u32)f2bf(h0) | ((u32)f2bf(h1) << 16);
                    __hip_atomic_store(&hw32[(grow * 512 + sb + cp * 2) >> 1], pk,
                                       __ATOMIC_RELAXED, AGENT);
                }
            }
        } else {
            if (t >= 1) {
                // stage g5=h5[t-1] (cols 0..511) and h6[t-2] (cols 512..1023)
                const u64* s1 = (const u64*)(h5g + ((t + 1) & 1) * 65536 +
                                             (size_t)b_ * 512 + cth * 32);
                const u64* s2 = (const u64*)(h6g + (t & 1) * 65536 +
                                             (size_t)b_ * 512 + cth * 32);
                u64* d1 = (u64*)&stg[r_ * 1032 + cth * 32];
                u64* d2 = (u64*)&stg[r_ * 1032 + 512 + cth * 32];
#pragma unroll
                for (int i = 0; i < 8; ++i) {
                    d1[i] = __hip_atomic_load(&s1[i], __ATOMIC_RELAXED, AGENT);
                    d2[i] = __hip_atomic_load(&s2[i], __ATOMIC_RELAXED, AGENT);
                }
            }
            __syncthreads();
            if (t >= 1 && t <= 512) {
                f32x4 a0 = {biasM, biasM, biasM, biasM};
                f32x4 a1 = {biasS, biasS, biasS, biasS};
                if (wv < 2) {  // z + xh
#pragma unroll
                    for (int kt = 0; kt < 16; ++kt) {
                        bf16x8 a = ldsA(stg, 1032, kt * 32, l15, q8);
                        a0 = MFMA(a, Bm[kt], a0);
                        a1 = MFMA(a, Bs[kt], a1);
                    }
#pragma unroll
                    for (int kt = 0; kt < 16; ++kt) {
                        bf16x8 a = ldsA(stg, 1032, 512 + kt * 32, l15, q8);
                        a0 = MFMA(a, Bm[16 + kt], a0);
                    }
                } else {       // r + ih
#pragma unroll
                    for (int kt = 0; kt < 16; ++kt) {
                        bf16x8 a = ldsA(stg, 1032, kt * 32, l15, q8);
                        a0 = MFMA(a, Bm[kt], a0);
                    }
#pragma unroll
                    for (int kt = 0; kt < 16; ++kt) {
                        bf16x8 a = ldsA(stg, 1032, 512 + kt * 32, l15, q8);
                        a0 = MFMA(a, Bm[16 + kt], a0);
                        a1 = MFMA(a, Bs[kt], a1);
                    }
                }
                {
                    int uM = gMain * 2 + ct, uS = (wv < 2 ? 4 + ct : 6 + ct);
#pragma unroll
                    for (int i = 0; i < 4; ++i) {
                        int rr = (lane >> 4) * 4 + i;
                        exch[uM * 272 + rr * 17 + l15] = a0[i];
                        exch[uS * 272 + rr * 17 + l15] = a1[i];
                    }
                }
                __syncthreads();
                {
                    u32* hw32 = (u32*)(h6g + ((t + 1) & 1) * 65536 + (size_t)row0 * 512);
                    int base0 = (0 + c2p) * 272 + grow * 17 + ccb;
                    int base1 = (2 + c2p) * 272 + grow * 17 + ccb;
                    int base2 = (4 + c2p) * 272 + grow * 17 + ccb;
                    int base3 = (6 + c2p) * 272 + grow * 17 + ccb;
                    float zv0 = exch[base0], zv1 = exch[base0 + 1];
                    float rv0 = exch[base1], rv1 = exch[base1 + 1];
                    float xh0 = exch[base2], xh1 = exch[base2 + 1];
                    float ih0 = exch[base3], ih1 = exch[base3 + 1];
                    float zg0 = sat01(0.2f * zv0 + 0.5f), zg1 = sat01(0.2f * zv1 + 0.5f);
                    float rt0 = sat01(0.2f * rv0 + 0.5f), rt1 = sat01(0.2f * rv1 + 0.5f);
                    float hh0 = ftanh(xh0 + rt0 * ih0), hh1 = ftanh(xh1 + rt1 * ih1);
                    float h0 = zg0 * hold0 + (1.f - zg0) * hh0;
                    float h1 = zg1 * hold1 + (1.f - zg1) * hh1;
                    hold0 = h0; hold1 = h1;
                    u32 pk = (u32)f2bf(h0) | ((u32)f2bf(h1) << 16);
                    __hip_atomic_store(&hw32[(grow * 512 + sb + cp * 2) >> 1], pk,
                                       __ATOMIC_RELAXED, AGENT);
                }
            }
            // dec[t-2] from staged h6[t-2]: this wg's slice picks one batch row
            if (t >= 2 && wv == 0) {
                const u16* hrow = &stg[slice * 1032 + 512 + lane * 8];
                bf16x8 hv = *(const bf16x8*)hrow;
                float s = 0.f;
#pragma unroll
                for (int j = 0; j < 8; ++j) s += bf2f((u16)hv[j]) * wdv[j];
#pragma unroll
                for (int off = 32; off >= 1; off >>= 1) s += __shfl_down(s, off);
                if (lane == 0) {
                    int bb = row0 + slice, tt = t - 2;
                    out[bb * 512 + tt] = ftanh(s + bdv) * dmsk[bb * 512 + tt];
                }
            }
        }

        // ---- per-rowgroup barrier (32 blocks each; no cross-rowgroup dataflow) ----
        __syncthreads();
        if (tid == 0) {
            __builtin_amdgcn_fence(__ATOMIC_RELEASE, "agent");
            __hip_atomic_fetch_add(&bar[rgp * 32], 1u, __ATOMIC_RELEASE, AGENT);
            const u32 target = 32u * (u32)(t + 1);
            while (__hip_atomic_load(&bar[rgp * 32], __ATOMIC_ACQUIRE, AGENT) < target)
                __builtin_amdgcn_s_sleep(1);
            __builtin_amdgcn_fence(__ATOMIC_ACQUIRE, "agent");
        }
        __syncthreads();
    }
}

extern "C" void kernel_launch(void* const* d_in, const int* in_sizes, int n_in,
                              void* d_out, int out_size, void* d_ws, size_t ws_size,
                              hipStream_t stream) {
    const float* zin = (const float*)d_in[0];
    const float* x2  = (const float*)d_in[1];
    const float* msk = (const float*)d_in[2];
    const float* dmk = (const float*)d_in[3];
    const float* W5  = (const float*)d_in[4];
    const float* U5  = (const float*)d_in[5];
    const float* bi5 = (const float*)d_in[6];
    const float* br5 = (const float*)d_in[7];
    const float* W6  = (const float*)d_in[8];
    const float* U6  = (const float*)d_in[9];
    const float* bi6 = (const float*)d_in[10];
    const float* br6 = (const float*)d_in[11];
    const float* Wd  = (const float*)d_in[12];
    const float* bd  = (const float*)d_in[13];
    float* out = (float*)d_out;

    // ws (u16 units): h5bf [2][128][512] | h6bf [2][128][512] | barrier (u32)
    u16* h5 = (u16*)d_ws;                      // 256 KB
    u16* h6 = h5 + 131072;                     // 256 KB
    u32* bar = (u32*)(h6 + 131072);            // 8 counters, 128B apart

    zero_ws_kernel<<<dim3(513), dim3(256), 0, stream>>>((u32*)d_ws);

    gru_fused<<<dim3(256), dim3(256), 0, stream>>>(
        zin, x2, msk, dmk, W5, U5, bi5, br5, W6, U6, bi6, br6,
        Wd, bd, out, h5, h6, bar);
}

// Round 7
// 3351.345 us; speedup vs baseline: 2.0120x; 2.0120x over previous
//
#include <hip/hip_runtime.h>
#include <hip/hip_bf16.h>

typedef unsigned short u16;
typedef unsigned int u32;
typedef unsigned long long u64;
typedef __attribute__((ext_vector_type(8))) short bf16x8;   // 8 bf16 (4 VGPRs)
typedef __attribute__((ext_vector_type(4))) float f32x4;

#define MFMA(a,b,c) __builtin_amdgcn_mfma_f32_16x16x32_bf16((a),(b),(c),0,0,0)
#define AGENT __HIP_MEMORY_SCOPE_AGENT

// All inputs/output FP32. Weights -> bf16 B-fragments once at start; h-state
// master fp32 in registers; ws h-buffers bf16, moved ONLY via agent-scope
// relaxed atomics (serviced at the coherence point; immune to per-XCD L2
// non-coherence). Barrier: per-rowgroup relaxed monotonic counter + explicit
// s_waitcnt vmcnt(0). NO agent fences — R6 showed fence(agent) lowers to
// buffer_wbl2/buffer_inv per step => 604 MB FETCH + dead time.
//
// B=128, T=512, LAT=256, F2=64, H=512, DIN=320, 3H=1536
// 256 wgs: wg<128 -> GRU5 (rowgroup=wg>>4 of 8, slice=wg&15 of 16, 32 h-cols)
//          wg>=128 -> GRU6 (same split)
// iter t (514): GRU5 -> h5[t] (t<=511); GRU6 -> h6[t-1] (1<=t<=512);
//               dec[t-2] from staged h6[t-2] (t>=2). Parity s&1 in ws.

__device__ __forceinline__ u16 f2bf(float f) {
    u32 u = __float_as_uint(f);
    u32 r = (u + 0x7fffu + ((u >> 16) & 1u)) >> 16;
    return (u16)r;
}
__device__ __forceinline__ float bf2f(u16 v) { return __uint_as_float(((u32)v) << 16); }
__device__ __forceinline__ float sat01(float x) { return fminf(1.f, fmaxf(0.f, x)); }
__device__ __forceinline__ float ftanh(float x) {
    x = fminf(10.f, fmaxf(-10.f, x));
    float e = __expf(2.f * x);
    return (e - 1.f) / (e + 1.f);
}

__device__ __forceinline__ bf16x8 loadB(const float* __restrict__ M, int k0, int colbase,
                                        int l15, int q8) {
    const float* p = M + (size_t)(k0 + q8) * 1536 + colbase + l15;
    bf16x8 r;
#pragma unroll
    for (int j = 0; j < 8; ++j) r[j] = (short)f2bf(p[(size_t)j * 1536]);
    return r;
}

__device__ __forceinline__ bf16x8 ldsA(const u16* s, int stride, int colbase, int l15, int q8) {
    return *(const bf16x8*)(s + l15 * stride + colbase + q8);
}

__global__ void zero_ws_kernel(u32* ws) {
    int i = blockIdx.x * 256 + threadIdx.x;
    if (i < 131328) ws[i] = 0u;
}

__global__ void __launch_bounds__(256, 1)
gru_fused(const float* __restrict__ zin, const float* __restrict__ x2,
          const float* __restrict__ msk, const float* __restrict__ dmsk,
          const float* __restrict__ W5, const float* __restrict__ U5,
          const float* __restrict__ bi5, const float* __restrict__ br5,
          const float* __restrict__ W6, const float* __restrict__ U6,
          const float* __restrict__ bi6, const float* __restrict__ br6,
          const float* __restrict__ Wd, const float* __restrict__ bdp,
          float* __restrict__ out, u16* __restrict__ h5g,
          u16* __restrict__ h6g, u32* __restrict__ bar)
{
    const int wg = blockIdx.x;
    const bool is6 = wg >= 128;
    const int id = is6 ? wg - 128 : wg;
    const int slice = id & 15;
    const int rgp = id >> 4;
    const int row0 = rgp << 4;
    const int sb = slice << 5;
    const int tid = threadIdx.x;
    const int wv = tid >> 6, lane = tid & 63;
    const int l15 = lane & 15, q8 = (lane >> 4) << 3;

    __shared__ u16 stg[16 * 1032];
    __shared__ float exch[8 * 16 * 17];

    const int ct = wv & 1;
    const int gMain = (wv < 2) ? 0 : 1;
    const int colMain = gMain * 512 + sb + ct * 16;
    const int colH = 1024 + sb + ct * 16;

    const float* bi = is6 ? bi6 : bi5;
    const float* br = is6 ? br6 : br5;
    const float biasM = bi[colMain + l15] + br[colMain + l15];
    const float biasS = (wv < 2) ? bi[colH + l15] : br[colH + l15];

    bf16x8 Bm[32], Bs[16];
    if (!is6) {
#pragma unroll
        for (int kt = 0; kt < 10; ++kt) Bm[kt] = loadB(W5, kt * 32, colMain, l15, q8);
#pragma unroll
        for (int kt = 0; kt < 16; ++kt) Bm[10 + kt] = loadB(U5, kt * 32, colMain, l15, q8);
        if (wv < 2) {
#pragma unroll
            for (int kt = 0; kt < 10; ++kt) Bs[kt] = loadB(W5, kt * 32, colH, l15, q8);
        } else {
#pragma unroll
            for (int kt = 0; kt < 16; ++kt) Bs[kt] = loadB(U5, kt * 32, colH, l15, q8);
        }
    } else {
#pragma unroll
        for (int kt = 0; kt < 16; ++kt) Bm[kt] = loadB(W6, kt * 32, colMain, l15, q8);
#pragma unroll
        for (int kt = 0; kt < 16; ++kt) Bm[16 + kt] = loadB(U6, kt * 32, colMain, l15, q8);
        if (wv < 2) {
#pragma unroll
            for (int kt = 0; kt < 16; ++kt) Bs[kt] = loadB(W6, kt * 32, colH, l15, q8);
        } else {
#pragma unroll
            for (int kt = 0; kt < 16; ++kt) Bs[kt] = loadB(U6, kt * 32, colH, l15, q8);
        }
    }

    float wdv[8]; float bdv = 0.f;
    if (is6 && wv == 0) {
#pragma unroll
        for (int j = 0; j < 8; ++j) wdv[j] = Wd[lane * 8 + j];
        bdv = bdp[0];
    }

    float hold0 = 0.f, hold1 = 0.f;
    const int grow = tid >> 4, cp = tid & 15;
    const int c2p = cp >> 3, ccb = (cp & 7) * 2;

    const int r_ = tid >> 4, cth = tid & 15;
    const int b_ = row0 + r_;

    for (int t = 0; t < 514; ++t) {
        if (!is6) {
            if (t < 512) {
                float mk = msk[b_ * 512 + t];
                for (int c = cth; c < 320; c += 16) {
                    float v = (c < 256) ? zin[b_ * 256 + c]
                                        : x2[(b_ * 512 + t) * 64 + (c - 256)];
                    stg[r_ * 840 + c] = f2bf(v * mk);
                }
                {
                    const u64* src = (const u64*)(h5g + ((t + 1) & 1) * 65536 +
                                                  (size_t)b_ * 512 + cth * 32);
                    u64* dst = (u64*)&stg[r_ * 840 + 320 + cth * 32];
#pragma unroll
                    for (int i = 0; i < 8; ++i)
                        dst[i] = __hip_atomic_load(&src[i], __ATOMIC_RELAXED, AGENT);
                }
                __syncthreads();
                f32x4 a0 = {biasM, biasM, biasM, biasM};
                f32x4 a1 = {biasS, biasS, biasS, biasS};
                if (wv < 2) {  // z + xh
#pragma unroll
                    for (int kt = 0; kt < 10; ++kt) {
                        bf16x8 a = ldsA(stg, 840, kt * 32, l15, q8);
                        a0 = MFMA(a, Bm[kt], a0);
                        a1 = MFMA(a, Bs[kt], a1);
                    }
#pragma unroll
                    for (int kt = 0; kt < 16; ++kt) {
                        bf16x8 a = ldsA(stg, 840, 320 + kt * 32, l15, q8);
                        a0 = MFMA(a, Bm[10 + kt], a0);
                    }
                } else {       // r + ih
#pragma unroll
                    for (int kt = 0; kt < 10; ++kt) {
                        bf16x8 a = ldsA(stg, 840, kt * 32, l15, q8);
                        a0 = MFMA(a, Bm[kt], a0);
                    }
#pragma unroll
                    for (int kt = 0; kt < 16; ++kt) {
                        bf16x8 a = ldsA(stg, 840, 320 + kt * 32, l15, q8);
                        a0 = MFMA(a, Bm[10 + kt], a0);
                        a1 = MFMA(a, Bs[kt], a1);
                    }
                }
                {
                    int uM = gMain * 2 + ct, uS = (wv < 2 ? 4 + ct : 6 + ct);
#pragma unroll
                    for (int i = 0; i < 4; ++i) {
                        int rr = (lane >> 4) * 4 + i;
                        exch[uM * 272 + rr * 17 + l15] = a0[i];
                        exch[uS * 272 + rr * 17 + l15] = a1[i];
                    }
                }
                __syncthreads();
                {
                    u32* hw32 = (u32*)(h5g + (t & 1) * 65536 + (size_t)row0 * 512);
                    int base0 = (0 + c2p) * 272 + grow * 17 + ccb;
                    int base1 = (2 + c2p) * 272 + grow * 17 + ccb;
                    int base2 = (4 + c2p) * 272 + grow * 17 + ccb;
                    int base3 = (6 + c2p) * 272 + grow * 17 + ccb;
                    float zv0 = exch[base0], zv1 = exch[base0 + 1];
                    float rv0 = exch[base1], rv1 = exch[base1 + 1];
                    float xh0 = exch[base2], xh1 = exch[base2 + 1];
                    float ih0 = exch[base3], ih1 = exch[base3 + 1];
                    float zg0 = sat01(0.2f * zv0 + 0.5f), zg1 = sat01(0.2f * zv1 + 0.5f);
                    float rt0 = sat01(0.2f * rv0 + 0.5f), rt1 = sat01(0.2f * rv1 + 0.5f);
                    float hh0 = ftanh(xh0 + rt0 * ih0), hh1 = ftanh(xh1 + rt1 * ih1);
                    float h0 = zg0 * hold0 + (1.f - zg0) * hh0;
                    float h1 = zg1 * hold1 + (1.f - zg1) * hh1;
                    hold0 = h0; hold1 = h1;
                    u32 pk = (u32)f2bf(h0) | ((u32)f2bf(h1) << 16);
                    __hip_atomic_store(&hw32[(grow * 512 + sb + cp * 2) >> 1], pk,
                                       __ATOMIC_RELAXED, AGENT);
                }
            }
        } else {
            if (t >= 1) {
                const u64* s1 = (const u64*)(h5g + ((t + 1) & 1) * 65536 +
                                             (size_t)b_ * 512 + cth * 32);
                const u64* s2 = (const u64*)(h6g + (t & 1) * 65536 +
                                             (size_t)b_ * 512 + cth * 32);
                u64* d1 = (u64*)&stg[r_ * 1032 + cth * 32];
                u64* d2 = (u64*)&stg[r_ * 1032 + 512 + cth * 32];
#pragma unroll
                for (int i = 0; i < 8; ++i) {
                    d1[i] = __hip_atomic_load(&s1[i], __ATOMIC_RELAXED, AGENT);
                    d2[i] = __hip_atomic_load(&s2[i], __ATOMIC_RELAXED, AGENT);
                }
            }
            __syncthreads();
            if (t >= 1 && t <= 512) {
                f32x4 a0 = {biasM, biasM, biasM, biasM};
                f32x4 a1 = {biasS, biasS, biasS, biasS};
                if (wv < 2) {  // z + xh
#pragma unroll
                    for (int kt = 0; kt < 16; ++kt) {
                        bf16x8 a = ldsA(stg, 1032, kt * 32, l15, q8);
                        a0 = MFMA(a, Bm[kt], a0);
                        a1 = MFMA(a, Bs[kt], a1);
                    }
#pragma unroll
                    for (int kt = 0; kt < 16; ++kt) {
                        bf16x8 a = ldsA(stg, 1032, 512 + kt * 32, l15, q8);
                        a0 = MFMA(a, Bm[16 + kt], a0);
                    }
                } else {       // r + ih
#pragma unroll
                    for (int kt = 0; kt < 16; ++kt) {
                        bf16x8 a = ldsA(stg, 1032, kt * 32, l15, q8);
                        a0 = MFMA(a, Bm[kt], a0);
                    }
#pragma unroll
                    for (int kt = 0; kt < 16; ++kt) {
                        bf16x8 a = ldsA(stg, 1032, 512 + kt * 32, l15, q8);
                        a0 = MFMA(a, Bm[16 + kt], a0);
                        a1 = MFMA(a, Bs[kt], a1);
                    }
                }
                {
                    int uM = gMain * 2 + ct, uS = (wv < 2 ? 4 + ct : 6 + ct);
#pragma unroll
                    for (int i = 0; i < 4; ++i) {
                        int rr = (lane >> 4) * 4 + i;
                        exch[uM * 272 + rr * 17 + l15] = a0[i];
                        exch[uS * 272 + rr * 17 + l15] = a1[i];
                    }
                }
                __syncthreads();
                {
                    u32* hw32 = (u32*)(h6g + ((t + 1) & 1) * 65536 + (size_t)row0 * 512);
                    int base0 = (0 + c2p) * 272 + grow * 17 + ccb;
                    int base1 = (2 + c2p) * 272 + grow * 17 + ccb;
                    int base2 = (4 + c2p) * 272 + grow * 17 + ccb;
                    int base3 = (6 + c2p) * 272 + grow * 17 + ccb;
                    float zv0 = exch[base0], zv1 = exch[base0 + 1];
                    float rv0 = exch[base1], rv1 = exch[base1 + 1];
                    float xh0 = exch[base2], xh1 = exch[base2 + 1];
                    float ih0 = exch[base3], ih1 = exch[base3 + 1];
                    float zg0 = sat01(0.2f * zv0 + 0.5f), zg1 = sat01(0.2f * zv1 + 0.5f);
                    float rt0 = sat01(0.2f * rv0 + 0.5f), rt1 = sat01(0.2f * rv1 + 0.5f);
                    float hh0 = ftanh(xh0 + rt0 * ih0), hh1 = ftanh(xh1 + rt1 * ih1);
                    float h0 = zg0 * hold0 + (1.f - zg0) * hh0;
                    float h1 = zg1 * hold1 + (1.f - zg1) * hh1;
                    hold0 = h0; hold1 = h1;
                    u32 pk = (u32)f2bf(h0) | ((u32)f2bf(h1) << 16);
                    __hip_atomic_store(&hw32[(grow * 512 + sb + cp * 2) >> 1], pk,
                                       __ATOMIC_RELAXED, AGENT);
                }
            }
            if (t >= 2 && wv == 0) {
                const u16* hrow = &stg[slice * 1032 + 512 + lane * 8];
                bf16x8 hv = *(const bf16x8*)hrow;
                float s = 0.f;
#pragma unroll
                for (int j = 0; j < 8; ++j) s += bf2f((u16)hv[j]) * wdv[j];
#pragma unroll
                for (int off = 32; off >= 1; off >>= 1) s += __shfl_down(s, off);
                if (lane == 0) {
                    int bb = row0 + slice, tt = t - 2;
                    out[bb * 512 + tt] = ftanh(s + bdv) * dmsk[bb * 512 + tt];
                }
            }
        }

        // ---- per-rowgroup barrier: relaxed atomics only, no cache-maintenance
        // fences. __syncthreads drains vmcnt (compiler-emitted) so all data
        // atomics completed at the coherence point before the counter RMW.
        __syncthreads();
        if (tid == 0) {
            asm volatile("s_waitcnt vmcnt(0)" ::: "memory");
            __hip_atomic_fetch_add(&bar[rgp * 32], 1u, __ATOMIC_RELAXED, AGENT);
            const u32 target = 32u * (u32)(t + 1);
            while (__hip_atomic_load(&bar[rgp * 32], __ATOMIC_RELAXED, AGENT) < target)
                __builtin_amdgcn_s_sleep(1);
        }
        __syncthreads();
    }
}

extern "C" void kernel_launch(void* const* d_in, const int* in_sizes, int n_in,
                              void* d_out, int out_size, void* d_ws, size_t ws_size,
                              hipStream_t stream) {
    const float* zin = (const float*)d_in[0];
    const float* x2  = (const float*)d_in[1];
    const float* msk = (const float*)d_in[2];
    const float* dmk = (const float*)d_in[3];
    const float* W5  = (const float*)d_in[4];
    const float* U5  = (const float*)d_in[5];
    const float* bi5 = (const float*)d_in[6];
    const float* br5 = (const float*)d_in[7];
    const float* W6  = (const float*)d_in[8];
    const float* U6  = (const float*)d_in[9];
    const float* bi6 = (const float*)d_in[10];
    const float* br6 = (const float*)d_in[11];
    const float* Wd  = (const float*)d_in[12];
    const float* bd  = (const float*)d_in[13];
    float* out = (float*)d_out;

    u16* h5 = (u16*)d_ws;
    u16* h6 = h5 + 131072;
    u32* bar = (u32*)(h6 + 131072);

    zero_ws_kernel<<<dim3(513), dim3(256), 0, stream>>>((u32*)d_ws);

    gru_fused<<<dim3(256), dim3(256), 0, stream>>>(
        zin, x2, msk, dmk, W5, U5, bi5, br5, W6, U6, bi6, br6,
        Wd, bd, out, h5, h6, bar);
}

// Round 8
// 2357.134 us; speedup vs baseline: 2.8607x; 1.4218x over previous
//
#include <hip/hip_runtime.h>
#include <hip/hip_bf16.h>

typedef unsigned short u16;
typedef unsigned int u32;
typedef unsigned long long u64;
typedef __attribute__((ext_vector_type(8))) short bf16x8;   // 8 bf16 (4 VGPRs)
typedef __attribute__((ext_vector_type(4))) float f32x4;

#define MFMA(a,b,c) __builtin_amdgcn_mfma_f32_16x16x32_bf16((a),(b),(c),0,0,0)
#define AGENT __HIP_MEMORY_SCOPE_AGENT

// Barrier-free dataflow sync: every h word is u32 = (step_tag<<16)|bf16.
// Producers fire relaxed agent-scope u64 atomic stores (two tagged cols);
// consumers poll the words until tags match. One IC round-trip per step on
// the critical path; no rendezvous, no vmcnt drains, no fences.
// Tags: h5[s]/h6[s] stamped s+1 (0 = unwritten; zeroed ws = initial state).
// WAR: peer overwrites auto-safe (data dependency); GRU5 overwriting h5[t-2]
// waits for GRU6's consumption counter cc5[rg] >= 16*(t-1) (off critical path).
//
// B=128, T=512, LAT=256, F2=64, H=512, DIN=320, 3H=1536
// 256 wgs: wg<128 -> GRU5 (rowgroup=wg>>4 of 8, slice=wg&15 of 16, 32 h-cols)
//          wg>=128 -> GRU6 (same split)
// iter t (514): GRU5 -> h5[t] (t<512); GRU6 -> h6[t-1] (1<=t<=512);
//               dec[t-2] from LDS-staged h6[t-2] (t>=2). Parity s&1 in ws.

__device__ __forceinline__ u16 f2bf(float f) {
    u32 u = __float_as_uint(f);
    u32 r = (u + 0x7fffu + ((u >> 16) & 1u)) >> 16;
    return (u16)r;
}
__device__ __forceinline__ float bf2f(u16 v) { return __uint_as_float(((u32)v) << 16); }
__device__ __forceinline__ float sat01(float x) { return fminf(1.f, fmaxf(0.f, x)); }
__device__ __forceinline__ float ftanh(float x) {
    x = fminf(10.f, fmaxf(-10.f, x));
    float e = __expf(2.f * x);
    return (e - 1.f) / (e + 1.f);
}

__device__ __forceinline__ bf16x8 loadB(const float* __restrict__ M, int k0, int colbase,
                                        int l15, int q8) {
    const float* p = M + (size_t)(k0 + q8) * 1536 + colbase + l15;
    bf16x8 r;
#pragma unroll
    for (int j = 0; j < 8; ++j) r[j] = (short)f2bf(p[(size_t)j * 1536]);
    return r;
}

__device__ __forceinline__ bf16x8 ldsA(const u16* s, int stride, int colbase, int l15, int q8) {
    return *(const bf16x8*)(s + l15 * stride + colbase + q8);
}

__global__ void zero_ws_kernel(u32* ws) {
    int i = blockIdx.x * 256 + threadIdx.x;
    if (i < 262400) ws[i] = 0u;  // h5w[2][128][512] + h6w[2][128][512] + cc5
}

__global__ void __launch_bounds__(256, 1)
gru_fused(const float* __restrict__ zin, const float* __restrict__ x2,
          const float* __restrict__ msk, const float* __restrict__ dmsk,
          const float* __restrict__ W5, const float* __restrict__ U5,
          const float* __restrict__ bi5, const float* __restrict__ br5,
          const float* __restrict__ W6, const float* __restrict__ U6,
          const float* __restrict__ bi6, const float* __restrict__ br6,
          const float* __restrict__ Wd, const float* __restrict__ bdp,
          float* __restrict__ out, u32* __restrict__ h5w,
          u32* __restrict__ h6w, u32* __restrict__ cc5)
{
    const int wg = blockIdx.x;
    const bool is6 = wg >= 128;
    const int id = is6 ? wg - 128 : wg;
    const int slice = id & 15;
    const int rgp = id >> 4;
    const int row0 = rgp << 4;
    const int sb = slice << 5;
    const int tid = threadIdx.x;
    const int wv = tid >> 6, lane = tid & 63;
    const int l15 = lane & 15, q8 = (lane >> 4) << 3;

    __shared__ u16 stg[16 * 1032];
    __shared__ float exch[8 * 16 * 17];

    const int ct = wv & 1;
    const int gMain = (wv < 2) ? 0 : 1;
    const int colMain = gMain * 512 + sb + ct * 16;
    const int colH = 1024 + sb + ct * 16;

    const float* bi = is6 ? bi6 : bi5;
    const float* br = is6 ? br6 : br5;
    const float biasM = bi[colMain + l15] + br[colMain + l15];
    const float biasS = (wv < 2) ? bi[colH + l15] : br[colH + l15];

    bf16x8 Bm[32], Bs[16];
    if (!is6) {
#pragma unroll
        for (int kt = 0; kt < 10; ++kt) Bm[kt] = loadB(W5, kt * 32, colMain, l15, q8);
#pragma unroll
        for (int kt = 0; kt < 16; ++kt) Bm[10 + kt] = loadB(U5, kt * 32, colMain, l15, q8);
        if (wv < 2) {
#pragma unroll
            for (int kt = 0; kt < 10; ++kt) Bs[kt] = loadB(W5, kt * 32, colH, l15, q8);
        } else {
#pragma unroll
            for (int kt = 0; kt < 16; ++kt) Bs[kt] = loadB(U5, kt * 32, colH, l15, q8);
        }
    } else {
#pragma unroll
        for (int kt = 0; kt < 16; ++kt) Bm[kt] = loadB(W6, kt * 32, colMain, l15, q8);
#pragma unroll
        for (int kt = 0; kt < 16; ++kt) Bm[16 + kt] = loadB(U6, kt * 32, colMain, l15, q8);
        if (wv < 2) {
#pragma unroll
            for (int kt = 0; kt < 16; ++kt) Bs[kt] = loadB(W6, kt * 32, colH, l15, q8);
        } else {
#pragma unroll
            for (int kt = 0; kt < 16; ++kt) Bs[kt] = loadB(U6, kt * 32, colH, l15, q8);
        }
    }

    float wdv[8]; float bdv = 0.f;
    if (is6 && wv == 0) {
#pragma unroll
        for (int j = 0; j < 8; ++j) wdv[j] = Wd[lane * 8 + j];
        bdv = bdp[0];
    }

    float hold0 = 0.f, hold1 = 0.f;
    const int grow = tid >> 4, cp = tid & 15;
    const int c2p = cp >> 3, ccb = (cp & 7) * 2;

    const int r_ = tid >> 4, cth = tid & 15;
    const int b_ = row0 + r_;

    for (int t = 0; t < 514; ++t) {
        if (!is6) {
            if (t < 512) {
                // ---- stage masked x (independent of h; issued first) ----
                float mk = msk[b_ * 512 + t];
                for (int c = cth; c < 320; c += 16) {
                    float v = (c < 256) ? zin[b_ * 256 + c]
                                        : x2[(b_ * 512 + t) * 64 + (c - 256)];
                    stg[r_ * 840 + c] = f2bf(v * mk);
                }
                // ---- poll-stage h5[t-1]: expect tag t ----
                {
                    const u64* src = (const u64*)(h5w + ((t + 1) & 1) * 65536 +
                                                  (size_t)b_ * 512);
                    const u32 exp = (u32)t;
                    u64 v[16];
                    while (true) {
                        bool ok = true;
#pragma unroll
                        for (int k = 0; k < 16; ++k)
                            v[k] = __hip_atomic_load(&src[cth + 16 * k], __ATOMIC_RELAXED, AGENT);
#pragma unroll
                        for (int k = 0; k < 16; ++k) {
                            u32 lo = (u32)v[k], hi = (u32)(v[k] >> 32);
                            if (((lo >> 16) != exp) | ((hi >> 16) != exp)) ok = false;
                        }
                        if (ok) break;
                        __builtin_amdgcn_s_sleep(1);
                    }
                    u16* dst = &stg[r_ * 840 + 320];
#pragma unroll
                    for (int k = 0; k < 16; ++k) {
                        u32 lo = (u32)v[k], hi = (u32)(v[k] >> 32);
                        int c = (cth + 16 * k) * 2;
                        *(u32*)&dst[c] = (lo & 0xffffu) | (hi << 16);
                    }
                }
                __syncthreads();
                // ---- MFMA: x-part K=320 (W5), h-part K=512 (U5) ----
                f32x4 a0 = {biasM, biasM, biasM, biasM};
                f32x4 a1 = {biasS, biasS, biasS, biasS};
                if (wv < 2) {  // z + xh
#pragma unroll
                    for (int kt = 0; kt < 10; ++kt) {
                        bf16x8 a = ldsA(stg, 840, kt * 32, l15, q8);
                        a0 = MFMA(a, Bm[kt], a0);
                        a1 = MFMA(a, Bs[kt], a1);
                    }
#pragma unroll
                    for (int kt = 0; kt < 16; ++kt) {
                        bf16x8 a = ldsA(stg, 840, 320 + kt * 32, l15, q8);
                        a0 = MFMA(a, Bm[10 + kt], a0);
                    }
                } else {       // r + ih
#pragma unroll
                    for (int kt = 0; kt < 10; ++kt) {
                        bf16x8 a = ldsA(stg, 840, kt * 32, l15, q8);
                        a0 = MFMA(a, Bm[kt], a0);
                    }
#pragma unroll
                    for (int kt = 0; kt < 16; ++kt) {
                        bf16x8 a = ldsA(stg, 840, 320 + kt * 32, l15, q8);
                        a0 = MFMA(a, Bm[10 + kt], a0);
                        a1 = MFMA(a, Bs[kt], a1);
                    }
                }
                {
                    int uM = gMain * 2 + ct, uS = (wv < 2 ? 4 + ct : 6 + ct);
#pragma unroll
                    for (int i = 0; i < 4; ++i) {
                        int rr = (lane >> 4) * 4 + i;
                        exch[uM * 272 + rr * 17 + l15] = a0[i];
                        exch[uS * 272 + rr * 17 + l15] = a1[i];
                    }
                }
                __syncthreads();
                // ---- WAR guard: GRU6 must have staged h5[t-2] ----
                if (t >= 2) {
                    if (tid == 0) {
                        const u32 need = 16u * (u32)(t - 1);
                        while (__hip_atomic_load(&cc5[rgp * 32], __ATOMIC_RELAXED, AGENT) < need)
                            __builtin_amdgcn_s_sleep(1);
                    }
                    __syncthreads();
                }
                // ---- gate math; fp32 regs; tagged u64 atomic store ----
                {
                    int base0 = (0 + c2p) * 272 + grow * 17 + ccb;
                    int base1 = (2 + c2p) * 272 + grow * 17 + ccb;
                    int base2 = (4 + c2p) * 272 + grow * 17 + ccb;
                    int base3 = (6 + c2p) * 272 + grow * 17 + ccb;
                    float zv0 = exch[base0], zv1 = exch[base0 + 1];
                    float rv0 = exch[base1], rv1 = exch[base1 + 1];
                    float xh0 = exch[base2], xh1 = exch[base2 + 1];
                    float ih0 = exch[base3], ih1 = exch[base3 + 1];
                    float zg0 = sat01(0.2f * zv0 + 0.5f), zg1 = sat01(0.2f * zv1 + 0.5f);
                    float rt0 = sat01(0.2f * rv0 + 0.5f), rt1 = sat01(0.2f * rv1 + 0.5f);
                    float hh0 = ftanh(xh0 + rt0 * ih0), hh1 = ftanh(xh1 + rt1 * ih1);
                    float h0 = zg0 * hold0 + (1.f - zg0) * hh0;
                    float h1 = zg1 * hold1 + (1.f - zg1) * hh1;
                    hold0 = h0; hold1 = h1;
                    const u32 tg = (u32)(t + 1) << 16;
                    u64 w = ((u64)(tg | (u32)f2bf(h1)) << 32) | (u64)(tg | (u32)f2bf(h0));
                    u64* dst = (u64*)(h5w + (t & 1) * 65536 + (size_t)row0 * 512);
                    __hip_atomic_store(&dst[(grow * 512 + sb + cp * 2) >> 1], w,
                                       __ATOMIC_RELAXED, AGENT);
                }
            }
        } else {
            // ---- poll-stage g5=h5[t-1] (expect t, t<=512) and h6[t-2] (expect t-1) ----
            if (t >= 1) {
                const u64* s2 = (const u64*)(h6w + (t & 1) * 65536 + (size_t)b_ * 512);
                const u32 exp2 = (u32)(t - 1);
                if (t <= 512) {
                    const u64* s1 = (const u64*)(h5w + ((t + 1) & 1) * 65536 + (size_t)b_ * 512);
                    const u32 exp1 = (u32)t;
                    u64 v1[16], v2[16];
                    while (true) {
                        bool ok = true;
#pragma unroll
                        for (int k = 0; k < 16; ++k) {
                            v1[k] = __hip_atomic_load(&s1[cth + 16 * k], __ATOMIC_RELAXED, AGENT);
                            v2[k] = __hip_atomic_load(&s2[cth + 16 * k], __ATOMIC_RELAXED, AGENT);
                        }
#pragma unroll
                        for (int k = 0; k < 16; ++k) {
                            u32 lo1 = (u32)v1[k], hi1 = (u32)(v1[k] >> 32);
                            u32 lo2 = (u32)v2[k], hi2 = (u32)(v2[k] >> 32);
                            if (((lo1 >> 16) != exp1) | ((hi1 >> 16) != exp1) |
                                ((lo2 >> 16) != exp2) | ((hi2 >> 16) != exp2)) ok = false;
                        }
                        if (ok) break;
                        __builtin_amdgcn_s_sleep(1);
                    }
#pragma unroll
                    for (int k = 0; k < 16; ++k) {
                        int c = (cth + 16 * k) * 2;
                        u32 lo = (u32)v1[k], hi = (u32)(v1[k] >> 32);
                        *(u32*)&stg[r_ * 1032 + c] = (lo & 0xffffu) | (hi << 16);
                        lo = (u32)v2[k]; hi = (u32)(v2[k] >> 32);
                        *(u32*)&stg[r_ * 1032 + 512 + c] = (lo & 0xffffu) | (hi << 16);
                    }
                } else {  // t == 513: only h6[511] needed (for dec)
                    u64 v2[16];
                    while (true) {
                        bool ok = true;
#pragma unroll
                        for (int k = 0; k < 16; ++k)
                            v2[k] = __hip_atomic_load(&s2[cth + 16 * k], __ATOMIC_RELAXED, AGENT);
#pragma unroll
                        for (int k = 0; k < 16; ++k) {
                            u32 lo = (u32)v2[k], hi = (u32)(v2[k] >> 32);
                            if (((lo >> 16) != exp2) | ((hi >> 16) != exp2)) ok = false;
                        }
                        if (ok) break;
                        __builtin_amdgcn_s_sleep(1);
                    }
#pragma unroll
                    for (int k = 0; k < 16; ++k) {
                        int c = (cth + 16 * k) * 2;
                        u32 lo = (u32)v2[k], hi = (u32)(v2[k] >> 32);
                        *(u32*)&stg[r_ * 1032 + 512 + c] = (lo & 0xffffu) | (hi << 16);
                    }
                }
            }
            __syncthreads();
            // consumption signal: h5[t-1] fully staged by this wg
            if (t >= 1 && t <= 512 && tid == 0)
                __hip_atomic_fetch_add(&cc5[rgp * 32], 1u, __ATOMIC_RELAXED, AGENT);
            if (t >= 1 && t <= 512) {
                f32x4 a0 = {biasM, biasM, biasM, biasM};
                f32x4 a1 = {biasS, biasS, biasS, biasS};
                if (wv < 2) {  // z + xh
#pragma unroll
                    for (int kt = 0; kt < 16; ++kt) {
                        bf16x8 a = ldsA(stg, 1032, kt * 32, l15, q8);
                        a0 = MFMA(a, Bm[kt], a0);
                        a1 = MFMA(a, Bs[kt], a1);
                    }
#pragma unroll
                    for (int kt = 0; kt < 16; ++kt) {
                        bf16x8 a = ldsA(stg, 1032, 512 + kt * 32, l15, q8);
                        a0 = MFMA(a, Bm[16 + kt], a0);
                    }
                } else {       // r + ih
#pragma unroll
                    for (int kt = 0; kt < 16; ++kt) {
                        bf16x8 a = ldsA(stg, 1032, kt * 32, l15, q8);
                        a0 = MFMA(a, Bm[kt], a0);
                    }
#pragma unroll
                    for (int kt = 0; kt < 16; ++kt) {
                        bf16x8 a = ldsA(stg, 1032, 512 + kt * 32, l15, q8);
                        a0 = MFMA(a, Bm[16 + kt], a0);
                        a1 = MFMA(a, Bs[kt], a1);
                    }
                }
                {
                    int uM = gMain * 2 + ct, uS = (wv < 2 ? 4 + ct : 6 + ct);
#pragma unroll
                    for (int i = 0; i < 4; ++i) {
                        int rr = (lane >> 4) * 4 + i;
                        exch[uM * 272 + rr * 17 + l15] = a0[i];
                        exch[uS * 272 + rr * 17 + l15] = a1[i];
                    }
                }
                __syncthreads();
                {
                    int base0 = (0 + c2p) * 272 + grow * 17 + ccb;
                    int base1 = (2 + c2p) * 272 + grow * 17 + ccb;
                    int base2 = (4 + c2p) * 272 + grow * 17 + ccb;
                    int base3 = (6 + c2p) * 272 + grow * 17 + ccb;
                    float zv0 = exch[base0], zv1 = exch[base0 + 1];
                    float rv0 = exch[base1], rv1 = exch[base1 + 1];
                    float xh0 = exch[base2], xh1 = exch[base2 + 1];
                    float ih0 = exch[base3], ih1 = exch[base3 + 1];
                    float zg0 = sat01(0.2f * zv0 + 0.5f), zg1 = sat01(0.2f * zv1 + 0.5f);
                    float rt0 = sat01(0.2f * rv0 + 0.5f), rt1 = sat01(0.2f * rv1 + 0.5f);
                    float hh0 = ftanh(xh0 + rt0 * ih0), hh1 = ftanh(xh1 + rt1 * ih1);
                    float h0 = zg0 * hold0 + (1.f - zg0) * hh0;
                    float h1 = zg1 * hold1 + (1.f - zg1) * hh1;
                    hold0 = h0; hold1 = h1;
                    const u32 tg = (u32)t << 16;   // h6[t-1] stamped (t-1)+1 = t
                    u64 w = ((u64)(tg | (u32)f2bf(h1)) << 32) | (u64)(tg | (u32)f2bf(h0));
                    u64* dst = (u64*)(h6w + ((t + 1) & 1) * 65536 + (size_t)row0 * 512);
                    __hip_atomic_store(&dst[(grow * 512 + sb + cp * 2) >> 1], w,
                                       __ATOMIC_RELAXED, AGENT);
                }
            }
            // dec[t-2] from LDS-staged h6[t-2]
            if (t >= 2 && wv == 0) {
                const u16* hrow = &stg[slice * 1032 + 512 + lane * 8];
                bf16x8 hv = *(const bf16x8*)hrow;
                float s = 0.f;
#pragma unroll
                for (int j = 0; j < 8; ++j) s += bf2f((u16)hv[j]) * wdv[j];
#pragma unroll
                for (int off = 32; off >= 1; off >>= 1) s += __shfl_down(s, off);
                if (lane == 0) {
                    int bb = row0 + slice, tt = t - 2;
                    out[bb * 512 + tt] = ftanh(s + bdv) * dmsk[bb * 512 + tt];
                }
            }
            __syncthreads();   // protect stg reuse across iterations
        }
    }
}

extern "C" void kernel_launch(void* const* d_in, const int* in_sizes, int n_in,
                              void* d_out, int out_size, void* d_ws, size_t ws_size,
                              hipStream_t stream) {
    const float* zin = (const float*)d_in[0];
    const float* x2  = (const float*)d_in[1];
    const float* msk = (const float*)d_in[2];
    const float* dmk = (const float*)d_in[3];
    const float* W5  = (const float*)d_in[4];
    const float* U5  = (const float*)d_in[5];
    const float* bi5 = (const float*)d_in[6];
    const float* br5 = (const float*)d_in[7];
    const float* W6  = (const float*)d_in[8];
    const float* U6  = (const float*)d_in[9];
    const float* bi6 = (const float*)d_in[10];
    const float* br6 = (const float*)d_in[11];
    const float* Wd  = (const float*)d_in[12];
    const float* bd  = (const float*)d_in[13];
    float* out = (float*)d_out;

    // ws (u32 units): h5w [2][128][512] | h6w [2][128][512] | cc5 (8 x 128B-spaced)
    u32* h5w = (u32*)d_ws;                 // 512 KB
    u32* h6w = h5w + 131072;               // 512 KB
    u32* cc5 = h6w + 131072;               // 1 KB

    zero_ws_kernel<<<dim3(1025), dim3(256), 0, stream>>>((u32*)d_ws);

    gru_fused<<<dim3(256), dim3(256), 0, stream>>>(
        zin, x2, msk, dmk, W5, U5, bi5, br5, W6, U6, bi6, br6,
        Wd, bd, out, h5w, h6w, cc5);
}